// Round 12
// baseline (272.099 us; speedup 1.0000x reference)
//
#include <hip/hip_runtime.h>
#include <hip/hip_bf16.h>
#include <stdint.h>

typedef unsigned short u16_t;
typedef __attribute__((ext_vector_type(8))) short short8;
typedef __attribute__((ext_vector_type(4))) float f32x4;
typedef __attribute__((ext_vector_type(4))) unsigned short us4;

__device__ __forceinline__ float bf2f(u16_t u) {
  union { unsigned int i; float f; } c; c.i = ((unsigned int)u) << 16; return c.f;
}
__device__ __forceinline__ u16_t f2bf(float f) {
  union { float f; unsigned int i; } c; c.f = f;
  unsigned int x = c.i;
  unsigned int r = x + 0x7fffu + ((x >> 16) & 1u);
  return (u16_t)(r >> 16);
}

__device__ __forceinline__ void gload_lds16(const u16_t* g, u16_t* l) {
  __builtin_amdgcn_global_load_lds(
      (const __attribute__((address_space(1))) void*)g,
      (__attribute__((address_space(3))) void*)(unsigned int)(uintptr_t)l,
      16, 0, 0);
}

struct Seg {
  const u16_t* Ah;
  const u16_t* Al;
  const u16_t* Bh;
  const u16_t* Bl;
  int boff;
};

struct GemmArgs {
  Seg segs[9];
  int nseg;
  int segs_per_split;
  int K;
  int ldA, ldB;
  long long sA, sB;
  float alpha;
  float* outf;
  long long sOut;
  long long sSplit;
  int ldT;
};

// Fused-split TN GEMM (used for feat and PV).
// MODE 0: Ah*Bh+Al*Bh+Ah*Bl; 2: Ah*Bh. NCH = k-chunks per barrier pair.
template<int BM, int BN, int MODE, bool PADB, int NCH = 4>
__global__ __launch_bounds__(256, 4) void gemm_tn(GemmArgs args) {
  constexpr int FM = BM / 32, FN = BN / 32;
  constexpr int AH_E = NCH * BM * 8;
  constexpr int AL_E = (MODE == 0) ? NCH * BM * 8 : 8;
  constexpr int BH_E = NCH * BN * 8;
  constexpr int BL_E = (MODE <= 1) ? NCH * BN * 8 : 8;
  constexpr int SM_E = AH_E + AL_E + BH_E + BL_E;
  __shared__ __align__(16) u16_t smem[SM_E];
  u16_t* aflat_h = smem;
  u16_t* aflat_l = smem + AH_E;
  u16_t* bflat_h = smem + AH_E + AL_E;
  u16_t* bflat_l = smem + AH_E + AL_E + BH_E;

  const int tid = threadIdx.x;
  const int wave = tid >> 6, lane = tid & 63;
  const int lhi = lane >> 4, llo = lane & 15;
  const int wr = wave >> 1, wc = wave & 1;
  const int nt = blockIdx.x, mt = blockIdx.y;
  const int b = blockIdx.z & 1, split = blockIdx.z >> 1;
  const int row0 = mt * BM, col0 = nt * BN;

  f32x4 acc[FM][FN];
  const f32x4 zero4 = {0.f, 0.f, 0.f, 0.f};
#pragma unroll
  for (int i = 0; i < FM; ++i)
#pragma unroll
    for (int j = 0; j < FN; ++j) acc[i][j] = zero4;

  constexpr int RA = BM * NCH / 256;
  constexpr int RB = BN * NCH / 256;

  const int s0 = split * args.segs_per_split;
  int s1 = s0 + args.segs_per_split;
  if (s1 > args.nseg) s1 = args.nseg;

  for (int s = s0; s < s1; ++s) {
    const u16_t* Abh = args.segs[s].Ah + (size_t)b * args.sA;
    const u16_t* Abl = args.segs[s].Al + (size_t)b * args.sA;
    const u16_t* Bbh = args.segs[s].Bh + (size_t)b * args.sB;
    const u16_t* Bbl = args.segs[s].Bl + (size_t)b * args.sB;
    const int boff = args.segs[s].boff;
    for (int k0 = 0; k0 < args.K; k0 += NCH * 8) {
      __syncthreads();
#pragma unroll
      for (int r = 0; r < RA; ++r) {
        int idx = r * 256 + tid;
        int chunk = idx / BM, m = idx % BM;
        size_t goff = (size_t)(row0 + m) * args.ldA + (k0 + chunk * 8);
        gload_lds16(Abh + goff, aflat_h + (size_t)idx * 8);
        if (MODE == 0)
          gload_lds16(Abl + goff, aflat_l + (size_t)idx * 8);
      }
#pragma unroll
      for (int r = 0; r < RB; ++r) {
        int idx = r * 256 + tid;
        int chunk = idx / BN, n = idx % BN;
        long long rowi;
        if (PADB) {
          int gn = col0 + n;
          rowi = (long long)((gn >> 6) + 1) * 66 + (gn & 63) + 1 + boff;
        } else {
          rowi = col0 + n;
        }
        size_t goff = (size_t)rowi * args.ldB + (k0 + chunk * 8);
        gload_lds16(Bbh + goff, bflat_h + (size_t)idx * 8);
        if (MODE <= 1)
          gload_lds16(Bbl + goff, bflat_l + (size_t)idx * 8);
      }
      __syncthreads();
#pragma unroll
      for (int kk = 0; kk < NCH / 4; ++kk) {
        const int ckA = (kk * 4 + lhi) * BM;
        const int ckB = (kk * 4 + lhi) * BN;
        short8 afh[FM], afl[FM], bfh[FN], bfl[FN];
#pragma unroll
        for (int i = 0; i < FM; ++i) {
          afh[i] = *(const short8*)(aflat_h + ((size_t)ckA + wr * (BM / 2) + i * 16 + llo) * 8);
          if (MODE == 0)
            afl[i] = *(const short8*)(aflat_l + ((size_t)ckA + wr * (BM / 2) + i * 16 + llo) * 8);
        }
#pragma unroll
        for (int j = 0; j < FN; ++j) {
          bfh[j] = *(const short8*)(bflat_h + ((size_t)ckB + wc * (BN / 2) + j * 16 + llo) * 8);
          if (MODE <= 1)
            bfl[j] = *(const short8*)(bflat_l + ((size_t)ckB + wc * (BN / 2) + j * 16 + llo) * 8);
        }
#pragma unroll
        for (int i = 0; i < FM; ++i)
#pragma unroll
          for (int j = 0; j < FN; ++j) {
            f32x4 t = acc[i][j];
            if (MODE <= 1)
              t = __builtin_amdgcn_mfma_f32_16x16x32_bf16(afh[i], bfl[j], t, 0, 0, 0);
            if (MODE == 0)
              t = __builtin_amdgcn_mfma_f32_16x16x32_bf16(afl[i], bfh[j], t, 0, 0, 0);
            t = __builtin_amdgcn_mfma_f32_16x16x32_bf16(afh[i], bfh[j], t, 0, 0, 0);
            acc[i][j] = t;
          }
      }
    }
  }

  float* outp = args.outf + (size_t)split * args.sSplit + (size_t)b * args.sOut;
#pragma unroll
  for (int i = 0; i < FM; ++i) {
    int mb = row0 + wr * (BM / 2) + i * 16 + lhi * 4;
#pragma unroll
    for (int j = 0; j < FN; ++j) {
      int n = col0 + wc * (BN / 2) + j * 16 + llo;
      f32x4 vv = acc[i][j] * args.alpha;
      *(f32x4*)(outp + (size_t)n * args.ldT + mb) = vv;
    }
  }
}

// ---- Fused QK (symmetric MODE1) + conv3x3 GEMM, block-role interleaved ----
// grid = 96 groups x 19 blocks: 11 QK (1056 total) + 8 conv (768 total).
struct QkConvArgs {
  const u16_t* fh;   // [2][4096][256]
  const u16_t* fl;
  float* sim;        // [2][4096][4096]
  const u16_t* W;    // w1h [9][256][512]
  const u16_t* X;    // xh  [2][4356][512]
  float* cpart;      // conv partials: 6 x [2][4096][256]
  long long sOut;    // 4096*256
  long long sSplit;  // FT_LL
};
__global__ __launch_bounds__(256, 4) void qk_conv_fused(QkConvArgs a) {
  __shared__ __align__(16) u16_t smem[16896];  // 33.8KB: conv lA(12288)+lB(4608); QK uses 12288 (+tbuf alias)
  const int tid = threadIdx.x;
  const int wave = tid >> 6, lane = tid & 63;
  const int lhi = lane >> 4, llo = lane & 15;
  const int wr = wave >> 1, wc = wave & 1;
  const int bid = blockIdx.x;
  const int grp = bid / 19, r19 = bid % 19;

  if (r19 < 11) {
    // ---------------- QK role ----------------
    int id = grp * 11 + r19;           // [0,1056)
    int b = id / 528;
    int t = id % 528, rr_ = 0;
    while (t >= 32 - rr_) { t -= 32 - rr_; ++rr_; }
    const int mt = rr_, nt = rr_ + t;
    const int row0 = mt * 128, col0 = nt * 128;
    u16_t* aflat_h = smem;
    u16_t* bflat_h = smem + 4096;
    u16_t* bflat_l = smem + 8192;
    const u16_t* Fh = a.fh + (size_t)b * 4096 * 256;
    const u16_t* Fl = a.fl + (size_t)b * 4096 * 256;

    f32x4 acc[4][4];
    const f32x4 zero4 = {0.f, 0.f, 0.f, 0.f};
#pragma unroll
    for (int i = 0; i < 4; ++i)
#pragma unroll
      for (int j = 0; j < 4; ++j) acc[i][j] = zero4;

    for (int k0 = 0; k0 < 256; k0 += 32) {
      __syncthreads();
#pragma unroll
      for (int rr = 0; rr < 2; ++rr) {
        int idx = rr * 256 + tid;
        int chunk = idx >> 7, m = idx & 127;
        gload_lds16(Fh + (size_t)(row0 + m) * 256 + k0 + chunk * 8, aflat_h + (size_t)idx * 8);
        gload_lds16(Fh + (size_t)(col0 + m) * 256 + k0 + chunk * 8, bflat_h + (size_t)idx * 8);
        gload_lds16(Fl + (size_t)(col0 + m) * 256 + k0 + chunk * 8, bflat_l + (size_t)idx * 8);
      }
      __syncthreads();
      short8 afh[4], bfh[4], bfl[4];
#pragma unroll
      for (int i = 0; i < 4; ++i)
        afh[i] = *(const short8*)(aflat_h + ((size_t)lhi * 128 + wr * 64 + i * 16 + llo) * 8);
#pragma unroll
      for (int j = 0; j < 4; ++j) {
        bfh[j] = *(const short8*)(bflat_h + ((size_t)lhi * 128 + wc * 64 + j * 16 + llo) * 8);
        bfl[j] = *(const short8*)(bflat_l + ((size_t)lhi * 128 + wc * 64 + j * 16 + llo) * 8);
      }
#pragma unroll
      for (int i = 0; i < 4; ++i)
#pragma unroll
        for (int j = 0; j < 4; ++j) {
          f32x4 tt = acc[i][j];
          tt = __builtin_amdgcn_mfma_f32_16x16x32_bf16(afh[i], bfl[j], tt, 0, 0, 0);
          tt = __builtin_amdgcn_mfma_f32_16x16x32_bf16(afh[i], bfh[j], tt, 0, 0, 0);
          acc[i][j] = tt;
        }
    }

    float* outp = a.sim + (size_t)b * 4096 * 4096;
#pragma unroll
    for (int i = 0; i < 4; ++i) {
      int mb = row0 + wr * 64 + i * 16 + lhi * 4;
#pragma unroll
      for (int j = 0; j < 4; ++j) {
        int n = col0 + wc * 64 + j * 16 + llo;
        f32x4 vv = acc[i][j] * 0.0625f;
        *(f32x4*)(outp + (size_t)n * 4096 + mb) = vv;
      }
    }
    if (nt != mt) {
      float* tb = (float*)smem;  // 32x132 f32
#pragma unroll
      for (int i = 0; i < 4; ++i) {
        __syncthreads();
#pragma unroll
        for (int j = 0; j < 4; ++j) {
#pragma unroll
          for (int r2 = 0; r2 < 4; ++r2) {
            int trow = wr * 16 + lhi * 4 + r2;
            int tcol = wc * 64 + j * 16 + llo;
            tb[trow * 132 + tcol] = acc[i][j][r2] * 0.0625f;
          }
        }
        __syncthreads();
#pragma unroll
        for (int it = 0; it < 4; ++it) {
          int idx = it * 256 + tid;
          int row = idx >> 5, c4 = idx & 31;
          int mg = row0 + (row >> 4) * 64 + i * 16 + (row & 15);
          f32x4 v4 = *(f32x4*)&tb[row * 132 + c4 * 4];
          *(f32x4*)(outp + (size_t)mg * 4096 + col0 + c4 * 4) = v4;
        }
      }
    }
  } else {
    // ---------------- conv role ----------------
    int id = grp * 8 + (r19 - 11);     // [0,768)
    const int nt = id & 31;
    const int mt = (id >> 5) & 1;
    const int z = id >> 6;             // [0,12)
    const int b = z & 1;
    const int rest = z >> 1;
    const int ty = rest % 3, kh = rest / 3;
    const int row0 = mt * 128;
    const int base = (2 * nt + ty) * 66;
    const u16_t* Xb = a.X + (size_t)b * 4356 * 512;
    const u16_t* Wt = a.W + (size_t)(ty * 3) * 131072;
    u16_t* lA = smem;                  // [3][4][128][8] flattened (12288)
    u16_t* lB = smem + 12288;          // [4*144*8] (4608)

    f32x4 acc[4][4];
    const f32x4 zero4 = {0.f, 0.f, 0.f, 0.f};
#pragma unroll
    for (int i = 0; i < 4; ++i)
#pragma unroll
      for (int j = 0; j < 4; ++j) acc[i][j] = zero4;

    for (int k0 = kh * 256; k0 < (kh + 1) * 256; k0 += 32) {
      __syncthreads();
#pragma unroll
      for (int t = 0; t < 3; ++t)
#pragma unroll
        for (int r = 0; r < 2; ++r) {
          int slot = r * 256 + tid;
          int chunk = slot >> 7, m = slot & 127;
          const u16_t* src = Wt + (size_t)t * 131072 + (size_t)(row0 + m) * 512 + k0 + chunk * 8;
          gload_lds16(src, lA + (size_t)t * 4096 + (size_t)slot * 8);
        }
#pragma unroll
      for (int r = 0; r < 2; ++r) {
        int idx = r * 256 + tid;
        int chunk = idx / 144, rr = idx % 144;
        gload_lds16(Xb + (size_t)(base + rr) * 512 + k0 + chunk * 8, lB + (size_t)idx * 8);
      }
      if (tid < 64) {
        int idx = 512 + tid;
        int chunk = idx / 144, rr = idx % 144;
        gload_lds16(Xb + (size_t)(base + rr) * 512 + k0 + chunk * 8, lB + (size_t)idx * 8);
      }
      __syncthreads();
#pragma unroll
      for (int t = 0; t < 3; ++t) {
        short8 af[4], bf[4];
#pragma unroll
        for (int i = 0; i < 4; ++i)
          af[i] = *(const short8*)(lA + (size_t)t * 4096 + ((size_t)lhi * 128 + wr * 64 + i * 16 + llo) * 8);
#pragma unroll
        for (int j = 0; j < 4; ++j) {
          int rB = wc * 66 + j * 16 + llo + t;
          bf[j] = *(const short8*)(lB + ((size_t)lhi * 144 + rB) * 8);
        }
#pragma unroll
        for (int i = 0; i < 4; ++i)
#pragma unroll
          for (int j = 0; j < 4; ++j)
            acc[i][j] = __builtin_amdgcn_mfma_f32_16x16x32_bf16(af[i], bf[j], acc[i][j], 0, 0, 0);
      }
    }

    float* outp = a.cpart + (size_t)(ty + 3 * kh) * a.sSplit + (size_t)b * a.sOut;
#pragma unroll
    for (int i = 0; i < 4; ++i) {
      int mb = row0 + wr * 64 + i * 16 + lhi * 4;
#pragma unroll
      for (int j = 0; j < 4; ++j) {
        int n = (nt << 7) + wc * 64 + j * 16 + llo;
        *(f32x4*)(outp + (size_t)n * 256 + mb) = acc[i][j];
      }
    }
  }
}

// ---- Fused wv2 GEMM (MODE0, 128x64) + row softmax, block-role interleaved ----
// grid = 512 groups x 17 blocks: 1 wv2 (512 total) + 16 softmax (8192 total).
struct Wv2SmArgs {
  const u16_t* v1h;  // [2][4096][256]
  const u16_t* v1l;
  const u16_t* w2h;  // [256][256]
  const u16_t* w2l;
  float* wpart;      // wv2 partials: 2 x [2][256][4096]  (d_ws head)
  long long sOut;    // 256*4096
  long long sSplit;  // FT_LL
  float* S;          // sim [2][4096][4096]
  u16_t* P;          // Pb
};
__global__ __launch_bounds__(256, 4) void wv2_softmax_fused(Wv2SmArgs a) {
  __shared__ __align__(16) u16_t smem[12288];  // 24.6KB wv2 staging; softmax carves 8 floats
  const int tid = threadIdx.x;
  const int bid = blockIdx.x;
  const int grp = bid / 17, r17 = bid % 17;

  if (r17 == 0) {
    // ---------------- wv2 role ----------------
    const int id = grp;                 // [0,512)
    const int wave = tid >> 6, lane = tid & 63;
    const int lhi = lane >> 4, llo = lane & 15;
    const int wr = wave >> 1, wc = wave & 1;
    const int nt = id & 3;
    const int mt = (id >> 2) & 31;
    const int z = id >> 7;              // [0,4)
    const int b = z & 1, split = z >> 1;
    const int row0 = mt * 128, col0 = nt * 64;
    u16_t* aflat_h = smem;
    u16_t* aflat_l = smem + 4096;
    u16_t* bflat_h = smem + 8192;
    u16_t* bflat_l = smem + 10240;
    const u16_t* Abh = a.v1h + (size_t)b * 4096 * 256 + split * 128;
    const u16_t* Abl = a.v1l + (size_t)b * 4096 * 256 + split * 128;
    const u16_t* Bbh = a.w2h + split * 128;
    const u16_t* Bbl = a.w2l + split * 128;

    f32x4 acc[4][2];
    const f32x4 zero4 = {0.f, 0.f, 0.f, 0.f};
#pragma unroll
    for (int i = 0; i < 4; ++i)
#pragma unroll
      for (int j = 0; j < 2; ++j) acc[i][j] = zero4;

    for (int k0 = 0; k0 < 128; k0 += 32) {
      __syncthreads();
#pragma unroll
      for (int r = 0; r < 2; ++r) {
        int idx = r * 256 + tid;
        int chunk = idx >> 7, m = idx & 127;
        size_t goff = (size_t)(row0 + m) * 256 + (k0 + chunk * 8);
        gload_lds16(Abh + goff, aflat_h + (size_t)idx * 8);
        gload_lds16(Abl + goff, aflat_l + (size_t)idx * 8);
      }
      {
        int idx = tid;
        int chunk = idx >> 6, n = idx & 63;
        size_t goff = (size_t)(col0 + n) * 256 + (k0 + chunk * 8);
        gload_lds16(Bbh + goff, bflat_h + (size_t)idx * 8);
        gload_lds16(Bbl + goff, bflat_l + (size_t)idx * 8);
      }
      __syncthreads();
      short8 afh[4], afl[4], bfh[2], bfl[2];
#pragma unroll
      for (int i = 0; i < 4; ++i) {
        afh[i] = *(const short8*)(aflat_h + ((size_t)lhi * 128 + wr * 64 + i * 16 + llo) * 8);
        afl[i] = *(const short8*)(aflat_l + ((size_t)lhi * 128 + wr * 64 + i * 16 + llo) * 8);
      }
#pragma unroll
      for (int j = 0; j < 2; ++j) {
        bfh[j] = *(const short8*)(bflat_h + ((size_t)lhi * 64 + wc * 32 + j * 16 + llo) * 8);
        bfl[j] = *(const short8*)(bflat_l + ((size_t)lhi * 64 + wc * 32 + j * 16 + llo) * 8);
      }
#pragma unroll
      for (int i = 0; i < 4; ++i)
#pragma unroll
        for (int j = 0; j < 2; ++j) {
          f32x4 t = acc[i][j];
          t = __builtin_amdgcn_mfma_f32_16x16x32_bf16(afh[i], bfl[j], t, 0, 0, 0);
          t = __builtin_amdgcn_mfma_f32_16x16x32_bf16(afl[i], bfh[j], t, 0, 0, 0);
          t = __builtin_amdgcn_mfma_f32_16x16x32_bf16(afh[i], bfh[j], t, 0, 0, 0);
          acc[i][j] = t;
        }
    }

    float* outp = a.wpart + (size_t)split * a.sSplit + (size_t)b * a.sOut;
#pragma unroll
    for (int i = 0; i < 4; ++i) {
      int mb = row0 + wr * 64 + i * 16 + lhi * 4;
#pragma unroll
      for (int j = 0; j < 2; ++j) {
        int n = col0 + wc * 32 + j * 16 + llo;
        *(f32x4*)(outp + (size_t)n * 4096 + mb) = acc[i][j];
      }
    }
  } else {
    // ---------------- softmax role ----------------
    const int row = grp * 16 + (r17 - 1);   // [0,8192)
    float* Sr = a.S + (size_t)row * 4096;
    u16_t* Pr = a.P + (size_t)row * 4096;
    const int t = tid;
    const int wave = t >> 6;
    float* red = (float*)smem;
    float* red2 = red + 4;
    f32x4 v[4];
    float vmax = -3.4e38f;
#pragma unroll
    for (int i = 0; i < 4; ++i) {
      v[i] = ((const f32x4*)Sr)[t + i * 256];
#pragma unroll
      for (int c = 0; c < 4; ++c) vmax = fmaxf(vmax, v[i][c]);
    }
#pragma unroll
    for (int off = 32; off; off >>= 1) vmax = fmaxf(vmax, __shfl_xor(vmax, off));
    if ((t & 63) == 0) red[wave] = vmax;
    __syncthreads();
    vmax = fmaxf(fmaxf(red[0], red[1]), fmaxf(red[2], red[3]));
    float sum = 0.f;
#pragma unroll
    for (int i = 0; i < 4; ++i)
#pragma unroll
      for (int c = 0; c < 4; ++c) { v[i][c] = __expf(v[i][c] - vmax); sum += v[i][c]; }
#pragma unroll
    for (int off = 32; off; off >>= 1) sum += __shfl_xor(sum, off);
    if ((t & 63) == 0) red2[wave] = sum;
    __syncthreads();
    sum = red2[0] + red2[1] + red2[2] + red2[3];
    float rs = 1.0f / sum;
#pragma unroll
    for (int i = 0; i < 4; ++i) {
      f32x4 o = v[i] * rs;
      __builtin_nontemporal_store(o, (f32x4*)Sr + t + i * 256);  // sim: write-once
      us4 pb;
#pragma unroll
      for (int c = 0; c < 4; ++c) pb[c] = f2bf(o[c]);
      ((us4*)Pr)[t + i * 256] = pb;  // Pb re-read by PV: keep cached
    }
  }
}

template<int LDT, bool PER_COL>
__global__ __launch_bounds__(256) void reduce_split(
    const float* __restrict__ part, long long sSplit, int ns,
    const float* __restrict__ scale, const float* __restrict__ bias,
    u16_t* __restrict__ oh, u16_t* __restrict__ ol, long long total) {
  long long i = ((long long)blockIdx.x * 256 + threadIdx.x) * 4;
  if (i >= total) return;
  f32x4 s = *(const f32x4*)(part + i);
  for (int p = 1; p < ns; ++p) s += *(const f32x4*)(part + (size_t)p * sSplit + i);
  f32x4 v;
  if (PER_COL) {
    int c = (int)(i & (LDT - 1));
    f32x4 bi = *(const f32x4*)(bias + c);
    if (scale) { f32x4 sc = *(const f32x4*)(scale + c); v = s * sc + bi; }
    else v = s + bi;
  } else {
    int r = (int)((i / LDT) & 255);
    float bi = bias[r];
    v = s + bi;
  }
  us4 h, l;
#pragma unroll
  for (int c2 = 0; c2 < 4; ++c2) {
    float vv = v[c2] > 0.f ? v[c2] : 0.f;
    u16_t hh = f2bf(vv);
    h[c2] = hh;
    l[c2] = f2bf(vv - bf2f(hh));
  }
  *(us4*)(oh + i) = h;
  if (ol) *(us4*)(ol + i) = l;
}

__global__ __launch_bounds__(256) void reduce_split_f32(
    const float* __restrict__ part, long long sSplit, int ns,
    float* __restrict__ out, long long total) {
  long long i = ((long long)blockIdx.x * 256 + threadIdx.x) * 4;
  if (i >= total) return;
  f32x4 s = *(const f32x4*)(part + i);
  for (int p = 1; p < ns; ++p) s += *(const f32x4*)(part + (size_t)p * sSplit + i);
  __builtin_nontemporal_store(s, (f32x4*)(out + i));  // ctx: write-once
}

// x [2][512][4096] -> padded transposed split xT [2][4356][512] (hi/lo bf16).
__global__ __launch_bounds__(256) void xprep(const float* __restrict__ x,
                                             u16_t* __restrict__ xh, u16_t* __restrict__ xl) {
  __shared__ float tile[64][65];
  const int b = blockIdx.z, c0 = blockIdx.y * 64, n0 = blockIdx.x * 64;
  const float* xb = x + ((size_t)b * 512 + c0) * 4096 + n0;
  const int t = threadIdx.x;
  const int tr = t >> 6, tc = t & 63;
#pragma unroll
  for (int rr = 0; rr < 16; ++rr) {
    int ci = tr + rr * 4;
    tile[ci][tc] = xb[(size_t)ci * 4096 + tc];
  }
  __syncthreads();
#pragma unroll
  for (int rr = 0; rr < 16; ++rr) {
    int nj = rr * 4 + tr;
    float v = tile[tc][nj];
    size_t rp = (size_t)(blockIdx.x + 1) * 66 + nj + 1;
    size_t o = ((size_t)b * 4356 + rp) * 512 + c0 + tc;
    u16_t hh = f2bf(v);
    xh[o] = hh;
    xl[o] = f2bf(v - bf2f(hh));
  }
}

// Fused prep: bn | wk split | wv2 split | wv1 remap | zeropad
__global__ __launch_bounds__(256) void prep_all(
    const float* __restrict__ wk, const float* __restrict__ wv2, const float* __restrict__ wv1,
    const float* __restrict__ g, const float* __restrict__ be, const float* __restrict__ mu,
    const float* __restrict__ var, const float* __restrict__ bkb,
    u16_t* __restrict__ wkh, u16_t* __restrict__ wkl,
    u16_t* __restrict__ w2h, u16_t* __restrict__ w2l,
    u16_t* __restrict__ w1h, float* __restrict__ bnA, float* __restrict__ bnB,
    u16_t* __restrict__ xh, u16_t* __restrict__ xl) {
  long long i = (long long)blockIdx.x * 256 + threadIdx.x;
  if (i < 256) {
    float s = g[i] * rsqrtf(var[i] + 1e-5f);
    bnA[i] = s;
    bnB[i] = (bkb[i] - mu[i]) * s + be[i];
    return;
  }
  i -= 256;
  if (i < 131072) {
    float v = wk[i];
    u16_t hh = f2bf(v);
    wkh[i] = hh; wkl[i] = f2bf(v - bf2f(hh));
    return;
  }
  i -= 131072;
  if (i < 65536) {
    float v = wv2[i];
    u16_t hh = f2bf(v);
    w2h[i] = hh; w2l[i] = f2bf(v - bf2f(hh));
    return;
  }
  i -= 65536;
  if (i < 1179648) {
    int tp = (int)(i / (256 * 512));
    int rem = (int)(i % (256 * 512));
    int o = rem / 512, c = rem % 512;
    w1h[i] = f2bf(wv1[((size_t)o * 512 + c) * 9 + tp]);
    return;
  }
  i -= 1179648;
  if (i < 133120) {
    int blk = (int)(i >> 8), t = (int)(i & 255);
    int rowi = blk % 260, b = blk / 260;
    int rp;
    if (rowi < 66) rp = rowi;
    else if (rowi < 132) rp = 4290 + (rowi - 66);
    else { int g2 = (rowi - 132) >> 1; rp = (g2 + 1) * 66 + ((rowi - 132) & 1) * 65; }
    size_t base = ((size_t)b * 4356 + rp) * 512;
    const us4 z = {0, 0, 0, 0};
    if (t < 128) *(us4*)(xh + base + (size_t)t * 4) = z;
    else *(us4*)(xl + base + (size_t)(t - 128) * 4) = z;
  }
}

extern "C" void kernel_launch(void* const* d_in, const int* in_sizes, int n_in,
                              void* d_out, int out_size, void* d_ws, size_t ws_size,
                              hipStream_t stream) {
  (void)in_sizes; (void)n_in; (void)out_size; (void)ws_size;
  const float* x   = (const float*)d_in[0];
  const float* wk  = (const float*)d_in[1];
  const float* bk  = (const float*)d_in[2];
  const float* gam = (const float*)d_in[3];
  const float* bet = (const float*)d_in[4];
  const float* mu  = (const float*)d_in[5];
  const float* var = (const float*)d_in[6];
  const float* wv1 = (const float*)d_in[7];
  const float* bv1 = (const float*)d_in[8];
  const float* wv2 = (const float*)d_in[9];
  const float* bv2 = (const float*)d_in[10];

  const int B = 2;
  const size_t XT_E  = (size_t)B * 4356 * 512;
  const size_t WK_E  = 256 * 512;
  const size_t WV1_E = 9ull * 256 * 512;
  const size_t WV2_E = 256 * 256;
  const size_t FT_E  = (size_t)B * 4096 * 256;
  const size_t P_E   = (size_t)B * 4096 * 4096;

  size_t off = 0;
  auto carve = [&](size_t bytes) -> char* {
    off = (off + 255) & ~(size_t)255;
    char* p = (char*)d_ws + off;
    off += bytes;
    return p;
  };
  u16_t* xh  = (u16_t*)carve(XT_E * 2);
  u16_t* xl  = (u16_t*)carve(XT_E * 2);
  u16_t* wkh = (u16_t*)carve(WK_E * 2);
  u16_t* wkl = (u16_t*)carve(WK_E * 2);
  u16_t* w1h = (u16_t*)carve(WV1_E * 2);
  u16_t* w2h = (u16_t*)carve(WV2_E * 2);
  u16_t* w2l = (u16_t*)carve(WV2_E * 2);
  u16_t* fth = (u16_t*)carve(FT_E * 2);
  u16_t* ftl = (u16_t*)carve(FT_E * 2);
  u16_t* v1h = (u16_t*)carve(FT_E * 2);
  u16_t* v1l = (u16_t*)carve(FT_E * 2);
  u16_t* vh  = (u16_t*)carve(FT_E * 2);
  u16_t* Pb  = (u16_t*)carve(P_E * 2);
  float* bnA = (float*)carve(256 * 4);
  float* bnB = (float*)carve(256 * 4);

  // Aliased scratch:
  //  big_part (Pb region): feat (2) / conv (6) partials, consumed before the
  //    wv2_softmax_fused launch writes Pb. max 6x8.4 = 50.3MB << 134MB.
  //  head_part (d_ws start, xh region dead after qk_conv_fused): wv2 partials
  //    (2x8.4MB), then PV partials (4x8.4MB) after wv2RED consumed them.
  float* big_part  = (float*)Pb;
  float* head_part = (float*)d_ws;

  float* ctx = (float*)d_out;
  float* sim = (float*)d_out + (size_t)B * 256 * 4096;

  const long long FT_LL = (long long)FT_E;

  prep_all<<<5897, 256, 0, stream>>>(wk, wv2, wv1, gam, bet, mu, var, bk,
                                     wkh, wkl, w2h, w2l, w1h, bnA, bnB, xh, xl);
  xprep<<<dim3(64, 8, 2), 256, 0, stream>>>(x, xh, xl);

  // ---- feat = relu(BN(wk @ x)): MODE0, 2 K-splits of 256
  {
    GemmArgs a = {};
    a.segs[0] = {wkh,       wkl,       xh,       xl,       0};
    a.segs[1] = {wkh + 256, wkl + 256, xh + 256, xl + 256, 0};
    a.nseg = 2; a.segs_per_split = 1; a.K = 256; a.ldA = 512; a.ldB = 512;
    a.sA = 0; a.sB = (long long)4356 * 512; a.alpha = 1.f;
    a.outf = big_part; a.sOut = (long long)4096 * 256; a.sSplit = FT_LL; a.ldT = 256;
    gemm_tn<64, 128, 0, true><<<dim3(32, 4, 4), 256, 0, stream>>>(a);
    reduce_split<256, true><<<2048, 256, 0, stream>>>(big_part, FT_LL, 2, bnA, bnB, fth, ftl, FT_LL);
  }
  // ---- QK (symmetric MODE1, writes sim) || conv3x3 (6 splits -> big_part)
  {
    QkConvArgs a;
    a.fh = fth; a.fl = ftl; a.sim = sim;
    a.W = w1h; a.X = xh; a.cpart = big_part;
    a.sOut = (long long)4096 * 256; a.sSplit = FT_LL;
    qk_conv_fused<<<1824, 256, 0, stream>>>(a);
    reduce_split<256, true><<<2048, 256, 0, stream>>>(big_part, FT_LL, 6, nullptr, bv1, v1h, v1l, FT_LL);
  }
  // ---- wv2 (MODE0 -> head_part) || softmax (sim -> sim, Pb)
  {
    Wv2SmArgs a;
    a.v1h = v1h; a.v1l = v1l; a.w2h = w2h; a.w2l = w2l;
    a.wpart = head_part; a.sOut = (long long)256 * 4096; a.sSplit = FT_LL;
    a.S = sim; a.P = Pb;
    wv2_softmax_fused<<<8704, 256, 0, stream>>>(a);
    reduce_split<4096, false><<<2048, 256, 0, stream>>>(head_part, FT_LL, 2, nullptr, bv2, vh, nullptr, FT_LL);
  }
  // ---- ctx = P @ v^T: MODE2, 128x128, NCH=8, 4 K-splits of 1024
  {
    GemmArgs a = {};
    for (int q = 0; q < 4; ++q)
      a.segs[q] = {Pb + (size_t)q * 1024, nullptr, vh + (size_t)q * 1024, nullptr, 0};
    a.nseg = 4; a.segs_per_split = 1; a.K = 1024; a.ldA = 4096; a.ldB = 4096;
    a.sA = (long long)4096 * 4096; a.sB = (long long)256 * 4096; a.alpha = 1.f;
    a.outf = head_part; a.sOut = (long long)256 * 4096; a.sSplit = FT_LL; a.ldT = 4096;
    gemm_tn<128, 128, 2, false, 8><<<dim3(2, 32, 8), 256, 0, stream>>>(a);
    reduce_split_f32<<<2048, 256, 0, stream>>>(head_part, FT_LL, 4, ctx, FT_LL);
  }
}

// Round 13
// 262.429 us; speedup vs baseline: 1.0368x; 1.0368x over previous
//
#include <hip/hip_runtime.h>
#include <hip/hip_bf16.h>
#include <stdint.h>

typedef unsigned short u16_t;
typedef __attribute__((ext_vector_type(8))) short short8;
typedef __attribute__((ext_vector_type(4))) float f32x4;
typedef __attribute__((ext_vector_type(4))) unsigned short us4;

__device__ __forceinline__ float bf2f(u16_t u) {
  union { unsigned int i; float f; } c; c.i = ((unsigned int)u) << 16; return c.f;
}
__device__ __forceinline__ u16_t f2bf(float f) {
  union { float f; unsigned int i; } c; c.f = f;
  unsigned int x = c.i;
  unsigned int r = x + 0x7fffu + ((x >> 16) & 1u);
  return (u16_t)(r >> 16);
}

__device__ __forceinline__ void gload_lds16(const u16_t* g, u16_t* l) {
  __builtin_amdgcn_global_load_lds(
      (const __attribute__((address_space(1))) void*)g,
      (__attribute__((address_space(3))) void*)(unsigned int)(uintptr_t)l,
      16, 0, 0);
}

struct Seg {
  const u16_t* Ah;
  const u16_t* Al;
  const u16_t* Bh;
  const u16_t* Bl;
  int boff;
};

struct GemmArgs {
  Seg segs[9];
  int nseg;
  int segs_per_split;
  int K;
  int ldA, ldB;
  long long sA, sB;
  float alpha;
  float* outf;
  long long sOut;
  long long sSplit;
  int ldT;
};

// Fused-split TN GEMM.  MODE 0: Ah*Bh+Al*Bh+Ah*Bl; 1: Ah*Bh+Ah*Bl; 2: Ah*Bh.
// NCH = k-chunks (of 8) staged per barrier pair (4 -> K_STEP 32, 8 -> 64).
// fp32 transposed store; SYMM: upper-triangle + coalesced mirror via LDS.
template<int BM, int BN, int MODE, bool PADB, bool SYMM, int NCH = 4>
__global__ __launch_bounds__(256, 4) void gemm_tn(GemmArgs args) {
  constexpr int FM = BM / 32, FN = BN / 32;
  constexpr int AH_E = NCH * BM * 8;
  constexpr int AL_E = (MODE == 0) ? NCH * BM * 8 : 8;
  constexpr int BH_E = NCH * BN * 8;
  constexpr int BL_E = (MODE <= 1) ? NCH * BN * 8 : 8;
  constexpr int SM_E = AH_E + AL_E + BH_E + BL_E;
  static_assert(!SYMM || (size_t)SM_E * 2 >= 32 * 132 * 4, "tbuf alias too small");
  __shared__ __align__(16) u16_t smem[SM_E];
  u16_t* aflat_h = smem;
  u16_t* aflat_l = smem + AH_E;
  u16_t* bflat_h = smem + AH_E + AL_E;
  u16_t* bflat_l = smem + AH_E + AL_E + BH_E;

  const int tid = threadIdx.x;
  const int wave = tid >> 6, lane = tid & 63;
  const int lhi = lane >> 4, llo = lane & 15;
  const int wr = wave >> 1, wc = wave & 1;
  int nt, mt, b, split;
  if (SYMM) {
    b = blockIdx.z; split = 0;
    int t = blockIdx.x, r = 0;
    while (t >= 32 - r) { t -= 32 - r; ++r; }
    mt = r; nt = r + t;
  } else {
    nt = blockIdx.x; mt = blockIdx.y;
    b = blockIdx.z & 1; split = blockIdx.z >> 1;
  }
  const int row0 = mt * BM, col0 = nt * BN;

  f32x4 acc[FM][FN];
  const f32x4 zero4 = {0.f, 0.f, 0.f, 0.f};
#pragma unroll
  for (int i = 0; i < FM; ++i)
#pragma unroll
    for (int j = 0; j < FN; ++j) acc[i][j] = zero4;

  constexpr int RA = BM * NCH / 256;
  constexpr int RB = BN * NCH / 256;

  const int s0 = split * args.segs_per_split;
  int s1 = s0 + args.segs_per_split;
  if (s1 > args.nseg) s1 = args.nseg;

  for (int s = s0; s < s1; ++s) {
    const u16_t* Abh = args.segs[s].Ah + (size_t)b * args.sA;
    const u16_t* Abl = args.segs[s].Al + (size_t)b * args.sA;
    const u16_t* Bbh = args.segs[s].Bh + (size_t)b * args.sB;
    const u16_t* Bbl = args.segs[s].Bl + (size_t)b * args.sB;
    const int boff = args.segs[s].boff;
    for (int k0 = 0; k0 < args.K; k0 += NCH * 8) {
      __syncthreads();
#pragma unroll
      for (int r = 0; r < RA; ++r) {
        int idx = r * 256 + tid;
        int chunk = idx / BM, m = idx % BM;
        size_t goff = (size_t)(row0 + m) * args.ldA + (k0 + chunk * 8);
        gload_lds16(Abh + goff, aflat_h + (size_t)idx * 8);
        if (MODE == 0)
          gload_lds16(Abl + goff, aflat_l + (size_t)idx * 8);
      }
#pragma unroll
      for (int r = 0; r < RB; ++r) {
        int idx = r * 256 + tid;
        int chunk = idx / BN, n = idx % BN;
        long long rowi;
        if (PADB) {
          int gn = col0 + n;
          rowi = (long long)((gn >> 6) + 1) * 66 + (gn & 63) + 1 + boff;
        } else {
          rowi = col0 + n;
        }
        size_t goff = (size_t)rowi * args.ldB + (k0 + chunk * 8);
        gload_lds16(Bbh + goff, bflat_h + (size_t)idx * 8);
        if (MODE <= 1)
          gload_lds16(Bbl + goff, bflat_l + (size_t)idx * 8);
      }
      __syncthreads();
#pragma unroll
      for (int kk = 0; kk < NCH / 4; ++kk) {
        const int ckA = (kk * 4 + lhi) * BM;
        const int ckB = (kk * 4 + lhi) * BN;
        short8 afh[FM], afl[FM], bfh[FN], bfl[FN];
#pragma unroll
        for (int i = 0; i < FM; ++i) {
          afh[i] = *(const short8*)(aflat_h + ((size_t)ckA + wr * (BM / 2) + i * 16 + llo) * 8);
          if (MODE == 0)
            afl[i] = *(const short8*)(aflat_l + ((size_t)ckA + wr * (BM / 2) + i * 16 + llo) * 8);
        }
#pragma unroll
        for (int j = 0; j < FN; ++j) {
          bfh[j] = *(const short8*)(bflat_h + ((size_t)ckB + wc * (BN / 2) + j * 16 + llo) * 8);
          if (MODE <= 1)
            bfl[j] = *(const short8*)(bflat_l + ((size_t)ckB + wc * (BN / 2) + j * 16 + llo) * 8);
        }
#pragma unroll
        for (int i = 0; i < FM; ++i)
#pragma unroll
          for (int j = 0; j < FN; ++j) {
            f32x4 t = acc[i][j];
            if (MODE <= 1)
              t = __builtin_amdgcn_mfma_f32_16x16x32_bf16(afh[i], bfl[j], t, 0, 0, 0);
            if (MODE == 0)
              t = __builtin_amdgcn_mfma_f32_16x16x32_bf16(afl[i], bfh[j], t, 0, 0, 0);
            t = __builtin_amdgcn_mfma_f32_16x16x32_bf16(afh[i], bfh[j], t, 0, 0, 0);
            acc[i][j] = t;
          }
      }
    }
  }

  float* outp = args.outf + (size_t)split * args.sSplit + (size_t)b * args.sOut;
#pragma unroll
  for (int i = 0; i < FM; ++i) {
    int mb = row0 + wr * (BM / 2) + i * 16 + lhi * 4;
#pragma unroll
    for (int j = 0; j < FN; ++j) {
      int n = col0 + wc * (BN / 2) + j * 16 + llo;
      f32x4 vv = acc[i][j] * args.alpha;
      *(f32x4*)(outp + (size_t)n * args.ldT + mb) = vv;
    }
  }
  if (SYMM) {
    if (nt != mt) {
      float* tb = (float*)smem;  // 32x132 f32, aliases staging smem post-K-loop
#pragma unroll
      for (int i = 0; i < FM; ++i) {
        __syncthreads();
#pragma unroll
        for (int j = 0; j < FN; ++j) {
#pragma unroll
          for (int r2 = 0; r2 < 4; ++r2) {
            int trow = wr * 16 + lhi * 4 + r2;
            int tcol = wc * 64 + j * 16 + llo;
            tb[trow * 132 + tcol] = acc[i][j][r2] * args.alpha;
          }
        }
        __syncthreads();
#pragma unroll
        for (int it = 0; it < 4; ++it) {
          int idx = it * 256 + tid;
          int row = idx >> 5, c4 = idx & 31;
          int mg = row0 + (row >> 4) * 64 + i * 16 + (row & 15);
          f32x4 v4 = *(f32x4*)&tb[row * 132 + c4 * 4];
          *(f32x4*)(outp + (size_t)mg * args.ldT + col0 + c4 * 4) = v4;
        }
      }
    }
  }
}

// Conv3x3 as 3 ty-splits; the 3 tx taps share ONE staged B tile with halo.
struct Conv3Args {
  const u16_t* W;
  const u16_t* X;
  float* outf;
  long long sOut;
  long long sSplit;
};
__global__ __launch_bounds__(256, 4) void conv3_gemm(Conv3Args a) {
  __shared__ __align__(16) u16_t lA[3][4][128][8];
  __shared__ __align__(16) u16_t lB[4 * 144 * 8];
  const int tid = threadIdx.x;
  const int wave = tid >> 6, lane = tid & 63;
  const int lhi = lane >> 4, llo = lane & 15;
  const int wr = wave >> 1, wc = wave & 1;
  const int nt = blockIdx.x, mt = blockIdx.y;
  const int b = blockIdx.z & 1, ty = blockIdx.z >> 1;
  const int row0 = mt * 128;
  const int base = (2 * nt + ty) * 66;
  const u16_t* Xb = a.X + (size_t)b * 4356 * 512;
  const u16_t* Wt = a.W + (size_t)(ty * 3) * 131072;

  f32x4 acc[4][4];
  const f32x4 zero4 = {0.f, 0.f, 0.f, 0.f};
#pragma unroll
  for (int i = 0; i < 4; ++i)
#pragma unroll
    for (int j = 0; j < 4; ++j) acc[i][j] = zero4;

  for (int k0 = 0; k0 < 512; k0 += 32) {
    __syncthreads();
#pragma unroll
    for (int t = 0; t < 3; ++t)
#pragma unroll
      for (int r = 0; r < 2; ++r) {
        int slot = r * 256 + tid;
        int chunk = slot >> 7, m = slot & 127;
        const u16_t* src = Wt + (size_t)t * 131072 + (size_t)(row0 + m) * 512 + k0 + chunk * 8;
        gload_lds16(src, &lA[t][0][0][0] + (size_t)slot * 8);
      }
#pragma unroll
    for (int r = 0; r < 2; ++r) {
      int idx = r * 256 + tid;
      int chunk = idx / 144, rr = idx % 144;
      gload_lds16(Xb + (size_t)(base + rr) * 512 + k0 + chunk * 8, lB + (size_t)idx * 8);
    }
    if (tid < 64) {
      int idx = 512 + tid;
      int chunk = idx / 144, rr = idx % 144;
      gload_lds16(Xb + (size_t)(base + rr) * 512 + k0 + chunk * 8, lB + (size_t)idx * 8);
    }
    __syncthreads();
#pragma unroll
    for (int t = 0; t < 3; ++t) {
      short8 af[4], bf[4];
#pragma unroll
      for (int i = 0; i < 4; ++i)
        af[i] = *(const short8*)&lA[t][lhi][wr * 64 + i * 16 + llo][0];
#pragma unroll
      for (int j = 0; j < 4; ++j) {
        int rB = wc * 66 + j * 16 + llo + t;
        bf[j] = *(const short8*)(lB + ((size_t)lhi * 144 + rB) * 8);
      }
#pragma unroll
      for (int i = 0; i < 4; ++i)
#pragma unroll
        for (int j = 0; j < 4; ++j)
          acc[i][j] = __builtin_amdgcn_mfma_f32_16x16x32_bf16(af[i], bf[j], acc[i][j], 0, 0, 0);
    }
  }

  float* outp = a.outf + (size_t)ty * a.sSplit + (size_t)b * a.sOut;
#pragma unroll
  for (int i = 0; i < 4; ++i) {
    int mb = row0 + wr * 64 + i * 16 + lhi * 4;
#pragma unroll
    for (int j = 0; j < 4; ++j) {
      int n = (nt << 7) + wc * 64 + j * 16 + llo;
      *(f32x4*)(outp + (size_t)n * 256 + mb) = acc[i][j];
    }
  }
}

template<int LDT, bool PER_COL>
__global__ __launch_bounds__(256) void reduce_split(
    const float* __restrict__ part, long long sSplit, int ns,
    const float* __restrict__ scale, const float* __restrict__ bias,
    u16_t* __restrict__ oh, u16_t* __restrict__ ol, long long total) {
  long long i = ((long long)blockIdx.x * 256 + threadIdx.x) * 4;
  if (i >= total) return;
  f32x4 s = *(const f32x4*)(part + i);
  for (int p = 1; p < ns; ++p) s += *(const f32x4*)(part + (size_t)p * sSplit + i);
  f32x4 v;
  if (PER_COL) {
    int c = (int)(i & (LDT - 1));
    f32x4 bi = *(const f32x4*)(bias + c);
    if (scale) { f32x4 sc = *(const f32x4*)(scale + c); v = s * sc + bi; }
    else v = s + bi;
  } else {
    int r = (int)((i / LDT) & 255);
    float bi = bias[r];
    v = s + bi;
  }
  us4 h, l;
#pragma unroll
  for (int c2 = 0; c2 < 4; ++c2) {
    float vv = v[c2] > 0.f ? v[c2] : 0.f;
    u16_t hh = f2bf(vv);
    h[c2] = hh;
    l[c2] = f2bf(vv - bf2f(hh));
  }
  *(us4*)(oh + i) = h;
  if (ol) *(us4*)(ol + i) = l;
}

__global__ __launch_bounds__(256) void reduce_split_f32(
    const float* __restrict__ part, long long sSplit, int ns,
    float* __restrict__ out, long long total) {
  long long i = ((long long)blockIdx.x * 256 + threadIdx.x) * 4;
  if (i >= total) return;
  f32x4 s = *(const f32x4*)(part + i);
  for (int p = 1; p < ns; ++p) s += *(const f32x4*)(part + (size_t)p * sSplit + i);
  __builtin_nontemporal_store(s, (f32x4*)(out + i));  // ctx: write-once, never re-read
}

// Row softmax over 4096, in-place fp32 + bf16 copy for PV.
__global__ __launch_bounds__(256) void softmax_k(float* S, u16_t* P) {
  const int row = blockIdx.x;
  float* Sr = S + (size_t)row * 4096;
  u16_t* Pr = P + (size_t)row * 4096;
  const int t = threadIdx.x;
  const int wave = t >> 6;
  f32x4 v[4];
  float vmax = -3.4e38f;
#pragma unroll
  for (int i = 0; i < 4; ++i) {
    v[i] = ((const f32x4*)Sr)[t + i * 256];
#pragma unroll
    for (int c = 0; c < 4; ++c) vmax = fmaxf(vmax, v[i][c]);
  }
#pragma unroll
  for (int off = 32; off; off >>= 1) vmax = fmaxf(vmax, __shfl_xor(vmax, off));
  __shared__ float red[4];
  if ((t & 63) == 0) red[wave] = vmax;
  __syncthreads();
  vmax = fmaxf(fmaxf(red[0], red[1]), fmaxf(red[2], red[3]));
  float sum = 0.f;
#pragma unroll
  for (int i = 0; i < 4; ++i)
#pragma unroll
    for (int c = 0; c < 4; ++c) { v[i][c] = __expf(v[i][c] - vmax); sum += v[i][c]; }
#pragma unroll
  for (int off = 32; off; off >>= 1) sum += __shfl_xor(sum, off);
  __shared__ float red2[4];
  if ((t & 63) == 0) red2[wave] = sum;
  __syncthreads();
  sum = red2[0] + red2[1] + red2[2] + red2[3];
  float rs = 1.0f / sum;
#pragma unroll
  for (int i = 0; i < 4; ++i) {
    f32x4 o = v[i] * rs;
    __builtin_nontemporal_store(o, (f32x4*)Sr + t + i * 256);  // sim: write-once
    us4 pb;
#pragma unroll
    for (int c = 0; c < 4; ++c) pb[c] = f2bf(o[c]);
    ((us4*)Pr)[t + i * 256] = pb;  // Pb re-read by PV: keep cached
  }
}

// x [2][512][4096] -> padded transposed split xT [2][4356][512] (hi/lo bf16).
__global__ __launch_bounds__(256) void xprep(const float* __restrict__ x,
                                             u16_t* __restrict__ xh, u16_t* __restrict__ xl) {
  __shared__ float tile[64][65];
  const int b = blockIdx.z, c0 = blockIdx.y * 64, n0 = blockIdx.x * 64;
  const float* xb = x + ((size_t)b * 512 + c0) * 4096 + n0;
  const int t = threadIdx.x;
  const int tr = t >> 6, tc = t & 63;
#pragma unroll
  for (int rr = 0; rr < 16; ++rr) {
    int ci = tr + rr * 4;
    tile[ci][tc] = xb[(size_t)ci * 4096 + tc];
  }
  __syncthreads();
#pragma unroll
  for (int rr = 0; rr < 16; ++rr) {
    int nj = rr * 4 + tr;
    float v = tile[tc][nj];
    size_t rp = (size_t)(blockIdx.x + 1) * 66 + nj + 1;
    size_t o = ((size_t)b * 4356 + rp) * 512 + c0 + tc;
    u16_t hh = f2bf(v);
    xh[o] = hh;
    xl[o] = f2bf(v - bf2f(hh));
  }
}

// Fused prep: bn | wk split | wv2 split | wv1 remap | zeropad
__global__ __launch_bounds__(256) void prep_all(
    const float* __restrict__ wk, const float* __restrict__ wv2, const float* __restrict__ wv1,
    const float* __restrict__ g, const float* __restrict__ be, const float* __restrict__ mu,
    const float* __restrict__ var, const float* __restrict__ bkb,
    u16_t* __restrict__ wkh, u16_t* __restrict__ wkl,
    u16_t* __restrict__ w2h, u16_t* __restrict__ w2l,
    u16_t* __restrict__ w1h, float* __restrict__ bnA, float* __restrict__ bnB,
    u16_t* __restrict__ xh, u16_t* __restrict__ xl) {
  long long i = (long long)blockIdx.x * 256 + threadIdx.x;
  if (i < 256) {
    float s = g[i] * rsqrtf(var[i] + 1e-5f);
    bnA[i] = s;
    bnB[i] = (bkb[i] - mu[i]) * s + be[i];
    return;
  }
  i -= 256;
  if (i < 131072) {
    float v = wk[i];
    u16_t hh = f2bf(v);
    wkh[i] = hh; wkl[i] = f2bf(v - bf2f(hh));
    return;
  }
  i -= 131072;
  if (i < 65536) {
    float v = wv2[i];
    u16_t hh = f2bf(v);
    w2h[i] = hh; w2l[i] = f2bf(v - bf2f(hh));
    return;
  }
  i -= 65536;
  if (i < 1179648) {
    int tp = (int)(i / (256 * 512));
    int rem = (int)(i % (256 * 512));
    int o = rem / 512, c = rem % 512;
    w1h[i] = f2bf(wv1[((size_t)o * 512 + c) * 9 + tp]);
    return;
  }
  i -= 1179648;
  if (i < 133120) {
    int blk = (int)(i >> 8), t = (int)(i & 255);
    int rowi = blk % 260, b = blk / 260;
    int rp;
    if (rowi < 66) rp = rowi;
    else if (rowi < 132) rp = 4290 + (rowi - 66);
    else { int g2 = (rowi - 132) >> 1; rp = (g2 + 1) * 66 + ((rowi - 132) & 1) * 65; }
    size_t base = ((size_t)b * 4356 + rp) * 512;
    const us4 z = {0, 0, 0, 0};
    if (t < 128) *(us4*)(xh + base + (size_t)t * 4) = z;
    else *(us4*)(xl + base + (size_t)(t - 128) * 4) = z;
  }
}

extern "C" void kernel_launch(void* const* d_in, const int* in_sizes, int n_in,
                              void* d_out, int out_size, void* d_ws, size_t ws_size,
                              hipStream_t stream) {
  (void)in_sizes; (void)n_in; (void)out_size; (void)ws_size;
  const float* x   = (const float*)d_in[0];
  const float* wk  = (const float*)d_in[1];
  const float* bk  = (const float*)d_in[2];
  const float* gam = (const float*)d_in[3];
  const float* bet = (const float*)d_in[4];
  const float* mu  = (const float*)d_in[5];
  const float* var = (const float*)d_in[6];
  const float* wv1 = (const float*)d_in[7];
  const float* bv1 = (const float*)d_in[8];
  const float* wv2 = (const float*)d_in[9];
  const float* bv2 = (const float*)d_in[10];

  const int B = 2;
  const size_t XT_E  = (size_t)B * 4356 * 512;
  const size_t WK_E  = 256 * 512;
  const size_t WV1_E = 9ull * 256 * 512;
  const size_t WV2_E = 256 * 256;
  const size_t FT_E  = (size_t)B * 4096 * 256;
  const size_t P_E   = (size_t)B * 4096 * 4096;

  size_t off = 0;
  auto carve = [&](size_t bytes) -> char* {
    off = (off + 255) & ~(size_t)255;
    char* p = (char*)d_ws + off;
    off += bytes;
    return p;
  };
  u16_t* xh  = (u16_t*)carve(XT_E * 2);
  u16_t* xl  = (u16_t*)carve(XT_E * 2);
  u16_t* wkh = (u16_t*)carve(WK_E * 2);
  u16_t* wkl = (u16_t*)carve(WK_E * 2);
  u16_t* w1h = (u16_t*)carve(WV1_E * 2);
  u16_t* w2h = (u16_t*)carve(WV2_E * 2);
  u16_t* w2l = (u16_t*)carve(WV2_E * 2);
  u16_t* fth = (u16_t*)carve(FT_E * 2);
  u16_t* ftl = (u16_t*)carve(FT_E * 2);
  u16_t* v1h = (u16_t*)carve(FT_E * 2);
  u16_t* v1l = (u16_t*)carve(FT_E * 2);
  u16_t* vh  = (u16_t*)carve(FT_E * 2);
  u16_t* Pb  = (u16_t*)carve(P_E * 2);
  float* bnA = (float*)carve(256 * 4);
  float* bnB = (float*)carve(256 * 4);

  // Aliased scratch: big_part (Pb region) for feat (2) / conv (3) partials,
  // all consumed before softmax writes Pb. pv_part (ws start) 33.5MB over
  // xh..fth region, all dead by PV time, rewritten per call.
  float* big_part = (float*)Pb;
  float* pv_part  = (float*)d_ws;

  float* ctx = (float*)d_out;
  float* sim = (float*)d_out + (size_t)B * 256 * 4096;

  const long long FT_LL = (long long)FT_E;

  prep_all<<<5897, 256, 0, stream>>>(wk, wv2, wv1, gam, bet, mu, var, bk,
                                     wkh, wkl, w2h, w2l, w1h, bnA, bnB, xh, xl);
  xprep<<<dim3(64, 8, 2), 256, 0, stream>>>(x, xh, xl);

  // ---- feat = relu(BN(wk @ x)): MODE0, 2 K-splits of 256
  {
    GemmArgs a = {};
    a.segs[0] = {wkh,       wkl,       xh,       xl,       0};
    a.segs[1] = {wkh + 256, wkl + 256, xh + 256, xl + 256, 0};
    a.nseg = 2; a.segs_per_split = 1; a.K = 256; a.ldA = 512; a.ldB = 512;
    a.sA = 0; a.sB = (long long)4356 * 512; a.alpha = 1.f;
    a.outf = big_part; a.sOut = (long long)4096 * 256; a.sSplit = FT_LL; a.ldT = 256;
    gemm_tn<64, 128, 0, true, false><<<dim3(32, 4, 4), 256, 0, stream>>>(a);
    reduce_split<256, true><<<2048, 256, 0, stream>>>(big_part, FT_LL, 2, bnA, bnB, fth, ftl, FT_LL);
  }
  // ---- QK: S = fth @ (fth+ftl)^T * Ck^-0.5, MODE1, symmetric upper-triangle
  {
    GemmArgs a = {};
    a.segs[0] = {fth, nullptr, fth, ftl, 0};
    a.nseg = 1; a.segs_per_split = 1; a.K = 256; a.ldA = 256; a.ldB = 256;
    a.sA = (long long)4096 * 256; a.sB = (long long)4096 * 256; a.alpha = 0.0625f;
    a.outf = sim; a.sOut = (long long)4096 * 4096; a.sSplit = 0; a.ldT = 4096;
    gemm_tn<128, 128, 1, false, true><<<dim3(528, 1, 2), 256, 0, stream>>>(a);
  }
  // ---- conv3x3 -> v1T partials: 3 ty-splits, tap-shared B staging
  {
    Conv3Args a;
    a.W = w1h; a.X = xh;
    a.outf = big_part; a.sOut = (long long)4096 * 256; a.sSplit = FT_LL;
    conv3_gemm<<<dim3(32, 2, 6), 256, 0, stream>>>(a);
    reduce_split<256, true><<<2048, 256, 0, stream>>>(big_part, FT_LL, 3, nullptr, bv1, v1h, v1l, FT_LL);
  }
  // ---- v = relu(wv2 @ v1 + bv2), flipped (M=4096, N=256), MODE0, 2 K-splits
  {
    GemmArgs a = {};
    a.segs[0] = {v1h,       v1l,       w2h,       w2l,       0};
    a.segs[1] = {v1h + 128, v1l + 128, w2h + 128, w2l + 128, 0};
    a.nseg = 2; a.segs_per_split = 1; a.K = 128; a.ldA = 256; a.ldB = 256;
    a.sA = (long long)4096 * 256; a.sB = 0; a.alpha = 1.f;
    a.outf = big_part; a.sOut = (long long)256 * 4096; a.sSplit = FT_LL; a.ldT = 4096;
    gemm_tn<128, 64, 0, false, false><<<dim3(4, 32, 4), 256, 0, stream>>>(a);
    reduce_split<4096, false><<<2048, 256, 0, stream>>>(big_part, FT_LL, 2, nullptr, bv2, vh, nullptr, FT_LL);
  }
  softmax_k<<<B * 4096, 256, 0, stream>>>(sim, Pb);
  // ---- ctx = P @ v^T: MODE2, 128x128, NCH=8 (K_STEP 64), 4 K-splits of 1024
  {
    GemmArgs a = {};
    for (int q = 0; q < 4; ++q)
      a.segs[q] = {Pb + (size_t)q * 1024, nullptr, vh + (size_t)q * 1024, nullptr, 0};
    a.nseg = 4; a.segs_per_split = 1; a.K = 1024; a.ldA = 4096; a.ldB = 4096;
    a.sA = (long long)4096 * 4096; a.sB = (long long)256 * 4096; a.alpha = 1.f;
    a.outf = pv_part; a.sOut = (long long)256 * 4096; a.sSplit = FT_LL; a.ldT = 4096;
    gemm_tn<128, 128, 2, false, false, 8><<<dim3(2, 32, 8), 256, 0, stream>>>(a);
    reduce_split_f32<<<2048, 256, 0, stream>>>(pv_part, FT_LL, 4, ctx, FT_LL);
  }
}